// Round 20
// baseline (46.773 us; speedup 1.0000x reference)
//
#include <hip/hip_runtime.h>
#include <stdint.h>
#include <math.h>

typedef __attribute__((ext_vector_type(8))) short short8;
typedef __attribute__((ext_vector_type(16))) float f32x16;

#define DEVI static __device__ __forceinline__

constexpr int D = 256;  // feature dim
constexpr float LOG2E = 1.4426950408889634f;
constexpr float LN2   = 0.6931471805599453f;
constexpr float SHIFT = 96.0f;   // log2-domain bias (R19-validated, absmax 0)

// ws layout (bytes)
constexpr size_t WS_EIMG  = 0;                   // 16 tiles x 16384 = 262144
constexpr size_t WS_ETERM = 262144;              // 512 f32
constexpr size_t WS_WSUM  = 264192;              // 1024 rowblk x 512 col = 2 MB
constexpr size_t WS_PART  = WS_WSUM + 2097152;   // 128 f32

DEVI unsigned int f2bf(float f) {
  unsigned int u = __float_as_uint(f);
  return (u + 0x7fffu + ((u >> 16) & 1u)) >> 16;  // RNE f32->bf16 (finite)
}
DEVI unsigned int cvtpk(float lo, float hi) {      // 1 instr: 2 f32 -> 2 bf16
  unsigned int r;
  asm("v_cvt_pk_bf16_f32 %0, %1, %2" : "=v"(r) : "v"(lo), "v"(hi));
  return r;
}
DEVI float d4(float4 x) { return x.x*x.x + x.y*x.y + x.z*x.z + x.w*x.w; }
DEVI float shflx(float v, int m) { return __shfl_xor(v, m, 64); }

// ---- prep: e -> B-fragment tile images (32-col tiles, scaled a*log2e) ----
// Tile t covers e-cols [32t, 32t+32). Frag for k-step s, lane (hi,c):
//   byte = t*16384 + s*1024 + (hi*32 + c)*16 holds granule g = 2s+hi
//   (k in [8g, 8g+8)) of col c.   (validated layout, absmax 0)
__global__ void prep_e(const float* __restrict__ e, const float* __restrict__ lsp,
                       char* __restrict__ eimg, float* __restrict__ eterm) {
  const int et = blockIdx.x, t = threadIdx.x;
  const int c = t >> 3, o = t & 7;   // col in tile, octant of 256 k
  const int gc = et * 32 + c;
  const float a = __expf(-2.0f * lsp[0]);
  const float sab = a * LOG2E;       // fold score scale into the image
  const float* s = e + (size_t)gc * D + o * 32;
  float sq = 0.0f;
  unsigned int w[16];
#pragma unroll
  for (int i = 0; i < 8; ++i) {
    float4 x = *(const float4*)(s + i * 4);
    sq += d4(x);
    w[2 * i]     = f2bf(sab * x.x) | (f2bf(sab * x.y) << 16);
    w[2 * i + 1] = f2bf(sab * x.z) | (f2bf(sab * x.w) << 16);
  }
  sq += shflx(sq, 1); sq += shflx(sq, 2); sq += shflx(sq, 4);  // 8-lane group
  char* base = eimg + (size_t)et * 16384;
#pragma unroll
  for (int i = 0; i < 4; ++i) {
    int g = o * 4 + i;  // 16B k-granule
    int phys = (g >> 1) * 1024 + (g & 1) * 512 + c * 16;
    uint4 pk; pk.x = w[4 * i]; pk.y = w[4 * i + 1];
    pk.z = w[4 * i + 2]; pk.w = w[4 * i + 3];
    *(uint4*)(base + phys) = pk;
  }
  if (o == 0) eterm[gc] = -0.5f * a * sq;   // natural-log units
}

// ---- main: 2048 blocks x 256 thr (4 waves; 4 blocks/CU = 4 independent
// barrier domains, 8 grid rounds for natural stage/compute pipelining).
// Block = 64 z-rows x 256 e-cols. Stage rows once -> LDS (XOR-swizzled) ->
// ONE barrier -> wave = 64 rows x 64 cols (2 tiles): per step 2 shared
// A-ds_reads feed 4 MFMA (ILP-4, half LDS traffic). NO-MAX shifted-sum
// epilogue (R19-exact), direct ws write. ----
__global__ __launch_bounds__(256, 4)
void lse_main(const float* __restrict__ z, const char* __restrict__ eimg,
              const float* __restrict__ lsp, float* __restrict__ wsum) {
  __shared__ char  zbuf[32768];   // 64 rows x 512B, granule-XOR-swizzled
  __shared__ float ztm[64];       // z row terms (log2 units, +SHIFT)

  const int tid = threadIdx.x;
  const int wid = tid >> 6, lane = tid & 63;
  const int l31 = lane & 31;      // z-row in row-group; C col = e-col
  const int hi  = lane >> 5;      // k-half of frags; C row-group bit
  const int bx = blockIdx.x;
  const int rowblk = bx >> 1, half = bx & 1;
  const float a = __expf(-2.0f * lsp[0]);
  const float ztf = -0.5f * a * LOG2E;

  // ---- stage 64 z-rows in 2 passes: 8 thr/row, 32 f32/thread ----
#pragma unroll
  for (int p = 0; p < 2; ++p) {
    const int srow = p * 32 + (tid >> 3);
    const int o = tid & 7;
    const float* src = z + ((size_t)rowblk * 64 + srow) * D + o * 32;
    float4 u0 = *(const float4*)(src),      u1 = *(const float4*)(src + 4);
    float4 u2 = *(const float4*)(src + 8),  u3 = *(const float4*)(src + 12);
    float4 u4 = *(const float4*)(src + 16), u5 = *(const float4*)(src + 20);
    float4 u6 = *(const float4*)(src + 24), u7 = *(const float4*)(src + 28);
    float sq = d4(u0) + d4(u1) + d4(u2) + d4(u3) +
               d4(u4) + d4(u5) + d4(u6) + d4(u7);
    sq += shflx(sq, 1); sq += shflx(sq, 2); sq += shflx(sq, 4);  // 8 thr/row
    uint4 a0, a1, a2, a3;
    a0.x = cvtpk(u0.x, u0.y); a0.y = cvtpk(u0.z, u0.w);
    a0.z = cvtpk(u1.x, u1.y); a0.w = cvtpk(u1.z, u1.w);
    a1.x = cvtpk(u2.x, u2.y); a1.y = cvtpk(u2.z, u2.w);
    a1.z = cvtpk(u3.x, u3.y); a1.w = cvtpk(u3.z, u3.w);
    a2.x = cvtpk(u4.x, u4.y); a2.y = cvtpk(u4.z, u4.w);
    a2.z = cvtpk(u5.x, u5.y); a2.w = cvtpk(u5.z, u5.w);
    a3.x = cvtpk(u6.x, u6.y); a3.y = cvtpk(u6.z, u6.w);
    a3.z = cvtpk(u7.x, u7.y); a3.w = cvtpk(u7.z, u7.w);
    char* rb = zbuf + srow * 512;
    const int key = srow & 31;
    *(uint4*)(rb + (((4 * o + 0) ^ key) * 16)) = a0;
    *(uint4*)(rb + (((4 * o + 1) ^ key) * 16)) = a1;
    *(uint4*)(rb + (((4 * o + 2) ^ key) * 16)) = a2;
    *(uint4*)(rb + (((4 * o + 3) ^ key) * 16)) = a3;
    if (o == 0) ztm[srow] = ztf * sq + SHIFT;
  }
  __syncthreads();   // the ONLY barrier

  // ---- K=256 single pass: wave owns tiles (half*8 + 2*wid) and +1 ----
  const char* bp0 = eimg + (size_t)(half * 8 + 2 * wid) * 16384 + (size_t)lane * 16;
  const char* bp1 = bp0 + 16384;

  f32x16 acc00, acc01, acc10, acc11;   // [rowgroup][tile]
#pragma unroll
  for (int i = 0; i < 16; ++i) { acc00[i] = 0.f; acc01[i] = 0.f;
                                 acc10[i] = 0.f; acc11[i] = 0.f; }
  // addr algebra: l31*512 + ((2s+hi)^l31)*16  ==  C0 ^ (s*32)
  const int C0 = l31 * 512 + ((hi * 16) ^ (l31 * 16));
  __builtin_amdgcn_s_setprio(1);
#pragma unroll
  for (int s = 0; s < 16; ++s) {
    const int slot = C0 ^ (s * 32);
    short8 A0 = *(const short8*)(zbuf + slot);            // rows 0..31
    short8 A1 = *(const short8*)(zbuf + slot + 16384);    // rows 32..63
    short8 B0 = *(const short8*)(bp0 + s * 1024);
    short8 B1 = *(const short8*)(bp1 + s * 1024);
    acc00 = __builtin_amdgcn_mfma_f32_32x32x16_bf16(A0, B0, acc00, 0, 0, 0);
    acc10 = __builtin_amdgcn_mfma_f32_32x32x16_bf16(A1, B0, acc10, 0, 0, 0);
    acc01 = __builtin_amdgcn_mfma_f32_32x32x16_bf16(A0, B1, acc01, 0, 0, 0);
    acc11 = __builtin_amdgcn_mfma_f32_32x32x16_bf16(A1, B1, acc11, 0, 0, 0);
  }
  __builtin_amdgcn_s_setprio(0);

  // ---- NO-MAX epilogue: lane = e-col (per tile); sum 2^(score+SHIFT) ----
  // C row = rg*32 + (r&3) + 8*(r>>2) + 4*hi -> ztm as float4 at 8j+4hi.
  float t0s = 0.f, t1s = 0.f;
#pragma unroll
  for (int j = 0; j < 4; ++j) {
    float4 z0 = *(const float4*)&ztm[8 * j + 4 * hi];
    float4 z1 = *(const float4*)&ztm[32 + 8 * j + 4 * hi];
    t0s += exp2f(acc00[4 * j]     + z0.x) + exp2f(acc10[4 * j]     + z1.x)
         + exp2f(acc00[4 * j + 1] + z0.y) + exp2f(acc10[4 * j + 1] + z1.y)
         + exp2f(acc00[4 * j + 2] + z0.z) + exp2f(acc10[4 * j + 2] + z1.z)
         + exp2f(acc00[4 * j + 3] + z0.w) + exp2f(acc10[4 * j + 3] + z1.w);
    t1s += exp2f(acc01[4 * j]     + z0.x) + exp2f(acc11[4 * j]     + z1.x)
         + exp2f(acc01[4 * j + 1] + z0.y) + exp2f(acc11[4 * j + 1] + z1.y)
         + exp2f(acc01[4 * j + 2] + z0.z) + exp2f(acc11[4 * j + 2] + z1.z)
         + exp2f(acc01[4 * j + 3] + z0.w) + exp2f(acc11[4 * j + 3] + z1.w);
  }
  t0s += shflx(t0s, 32);   // other 32 rows live in partner lane
  t1s += shflx(t1s, 32);
  if (hi == 0) {   // each col owned by exactly one lane -> direct store
    const int colbase = half * 256 + 2 * wid * 32;
    wsum[(size_t)rowblk * 512 + colbase + l31]      = t0s;
    wsum[(size_t)rowblk * 512 + colbase + 32 + l31] = t1s;
  }
}

// ---- merge the 8 row-blocks of each 512-row window, add eterm, reduce ----
__global__ void merge_b(const float* __restrict__ wsum,
                        const float* __restrict__ eterm, float* __restrict__ partial) {
  __shared__ float sh[512];
  const int b = blockIdx.x, t = threadIdx.x;
  float s = 0.0f;
#pragma unroll
  for (int i = 0; i < 8; ++i)
    s += wsum[(size_t)(8 * b + i) * 512 + t];
  sh[t] = LN2 * (log2f(s) - SHIFT) + eterm[t];   // back to natural units
  __syncthreads();
  for (int st = 256; st > 0; st >>= 1) {
    if (t < st) sh[t] += sh[t + st];
    __syncthreads();
  }
  if (t == 0) partial[b] = sh[0];
}

__global__ void final_k(const float* __restrict__ partial,
                        const float* __restrict__ lsp, float* __restrict__ out) {
  __shared__ float sh[128];
  const int t = threadIdx.x;
  sh[t] = partial[t];
  __syncthreads();
  for (int st = 64; st > 0; st >>= 1) {
    if (t < st) sh[t] += sh[t + st];
    __syncthreads();
  }
  if (t == 0) {
    float ls = lsp[0];
    out[0] = -sh[0] / 65536.0f + 128.0f * (2.0f * ls - 1.0f) + logf(512.0f);
  }
}

extern "C" void kernel_launch(void* const* d_in, const int* in_sizes, int n_in,
                              void* d_out, int out_size, void* d_ws, size_t ws_size,
                              hipStream_t stream) {
  const float* z   = (const float*)d_in[0];
  const float* e   = (const float*)d_in[1];
  const float* lsp = (const float*)d_in[2];
  float* out = (float*)d_out;
  char* ws = (char*)d_ws;
  char*  eimg    = ws + WS_EIMG;
  float* eterm   = (float*)(ws + WS_ETERM);
  float* wsum    = (float*)(ws + WS_WSUM);
  float* partial = (float*)(ws + WS_PART);

  prep_e<<<dim3(16), dim3(256), 0, stream>>>(e, lsp, eimg, eterm);
  lse_main<<<dim3(2048), dim3(256), 0, stream>>>(z, eimg, lsp, wsum);
  merge_b<<<dim3(128), dim3(512), 0, stream>>>(wsum, eterm, partial);
  final_k<<<dim3(1), dim3(128), 0, stream>>>(partial, lsp, out);
}

// Round 21
// 44.179 us; speedup vs baseline: 1.0587x; 1.0587x over previous
//
#include <hip/hip_runtime.h>
#include <stdint.h>
#include <math.h>

typedef __attribute__((ext_vector_type(8))) short short8;
typedef __attribute__((ext_vector_type(16))) float f32x16;

#define DEVI static __device__ __forceinline__

constexpr int D = 256;  // feature dim
constexpr float LOG2E = 1.4426950408889634f;
constexpr float LN2   = 0.6931471805599453f;
constexpr float SHIFT = 96.0f;   // log2-domain bias: args in [-204,+27], no
                                 // overflow (needs 9.3-sigma z.e), underflow
                                 // only for terms 2^-100 below block max.

// ws layout (bytes)
constexpr size_t WS_EIMG  = 0;                   // 16 tiles x 16384 = 262144
constexpr size_t WS_ETERM = 262144;              // 512 f32
constexpr size_t WS_WSUM  = 264192;              // 1024 rowblk x 512 col = 2 MB
constexpr size_t WS_PART  = WS_WSUM + 2097152;   // 128 f32

DEVI unsigned int f2bf(float f) {
  unsigned int u = __float_as_uint(f);
  return (u + 0x7fffu + ((u >> 16) & 1u)) >> 16;  // RNE f32->bf16 (finite)
}
DEVI unsigned int cvtpk(float lo, float hi) {      // 1 instr: 2 f32 -> 2 bf16
  unsigned int r;
  asm("v_cvt_pk_bf16_f32 %0, %1, %2" : "=v"(r) : "v"(lo), "v"(hi));
  return r;
}
DEVI float d4(float4 x) { return x.x*x.x + x.y*x.y + x.z*x.z + x.w*x.w; }
DEVI float shflx(float v, int m) { return __shfl_xor(v, m, 64); }

// ---- prep: e -> B-fragment tile images (32-col tiles, scaled a*log2e) ----
// Tile t covers e-cols [32t, 32t+32). Frag for k-step s, lane (hi,c):
//   byte = t*16384 + s*1024 + (hi*32 + c)*16 holds granule g = 2s+hi
//   (k in [8g, 8g+8)) of col c.   (validated layout, absmax 0)
__global__ void prep_e(const float* __restrict__ e, const float* __restrict__ lsp,
                       char* __restrict__ eimg, float* __restrict__ eterm) {
  const int et = blockIdx.x, t = threadIdx.x;
  const int c = t >> 3, o = t & 7;   // col in tile, octant of 256 k
  const int gc = et * 32 + c;
  const float a = __expf(-2.0f * lsp[0]);
  const float sab = a * LOG2E;       // fold score scale into the image
  const float* s = e + (size_t)gc * D + o * 32;
  float sq = 0.0f;
  unsigned int w[16];
#pragma unroll
  for (int i = 0; i < 8; ++i) {
    float4 x = *(const float4*)(s + i * 4);
    sq += d4(x);
    w[2 * i]     = f2bf(sab * x.x) | (f2bf(sab * x.y) << 16);
    w[2 * i + 1] = f2bf(sab * x.z) | (f2bf(sab * x.w) << 16);
  }
  sq += shflx(sq, 1); sq += shflx(sq, 2); sq += shflx(sq, 4);  // 8-lane group
  char* base = eimg + (size_t)et * 16384;
#pragma unroll
  for (int i = 0; i < 4; ++i) {
    int g = o * 4 + i;  // 16B k-granule
    int phys = (g >> 1) * 1024 + (g & 1) * 512 + c * 16;
    uint4 pk; pk.x = w[4 * i]; pk.y = w[4 * i + 1];
    pk.z = w[4 * i + 2]; pk.w = w[4 * i + 3];
    *(uint4*)(base + phys) = pk;
  }
  if (o == 0) eterm[gc] = -0.5f * a * sq;   // natural-log units
}

// ---- main: 2048 blocks x 512 thr (8 waves; 4 waves/SIMD, 2 blocks/CU).
// Block = 64 z-rows x 256 e-cols (col-half). Stage rows once into LDS (bf16,
// XOR-swizzled) -> ONE barrier -> each wave: 32 e-cols over K=256, B(e) from
// L2 image with 4-deep prefetch queue, A(z) from LDS. NO-MAX single-pass
// shifted-sum LSE per col (exact: see SHIFT analysis), direct ws write. ----
__global__ __launch_bounds__(512, 4)
void lse_main(const float* __restrict__ z, const char* __restrict__ eimg,
              const float* __restrict__ lsp, float* __restrict__ wsum) {
  __shared__ char  zbuf[32768];   // 64 rows x 512B, granule-XOR-swizzled
  __shared__ float ztm[64];       // z row terms (log2 units, +SHIFT)

  const int tid = threadIdx.x;
  const int wid = tid >> 6, lane = tid & 63;
  const int l31 = lane & 31;      // z-row in row-group; C col = e-col
  const int hi  = lane >> 5;      // k-half of frags; C row-group bit
  const int bx = blockIdx.x;
  const int rowblk = bx >> 1, half = bx & 1;
  const float a = __expf(-2.0f * lsp[0]);
  const float ztf = -0.5f * a * LOG2E;

  // ---- stage 64 z-rows: 16 thr/row, thread handles rows srow & srow+32 ----
  {
    const int srow = tid >> 4;          // 0..31
    const int gp = (tid & 15) * 2;      // granule-pair base
    const float* p0 = z + ((size_t)rowblk * 64 + srow) * D + gp * 8;
    const float* p1 = p0 + (size_t)32 * D;
    float4 u0 = *(const float4*)(p0),     u1 = *(const float4*)(p0 + 4);
    float4 u2 = *(const float4*)(p0 + 8), u3 = *(const float4*)(p0 + 12);
    float4 w0 = *(const float4*)(p1),     w1 = *(const float4*)(p1 + 4);
    float4 w2 = *(const float4*)(p1 + 8), w3 = *(const float4*)(p1 + 12);
    float squ = d4(u0) + d4(u1) + d4(u2) + d4(u3);
    float sqw = d4(w0) + d4(w1) + d4(w2) + d4(w3);
    squ += shflx(squ, 1); squ += shflx(squ, 2);
    squ += shflx(squ, 4); squ += shflx(squ, 8);    // 16 thr per row
    sqw += shflx(sqw, 1); sqw += shflx(sqw, 2);
    sqw += shflx(sqw, 4); sqw += shflx(sqw, 8);
    uint4 a0, a1, b0, b1;
    a0.x = cvtpk(u0.x, u0.y); a0.y = cvtpk(u0.z, u0.w);
    a0.z = cvtpk(u1.x, u1.y); a0.w = cvtpk(u1.z, u1.w);
    a1.x = cvtpk(u2.x, u2.y); a1.y = cvtpk(u2.z, u2.w);
    a1.z = cvtpk(u3.x, u3.y); a1.w = cvtpk(u3.z, u3.w);
    b0.x = cvtpk(w0.x, w0.y); b0.y = cvtpk(w0.z, w0.w);
    b0.z = cvtpk(w1.x, w1.y); b0.w = cvtpk(w1.z, w1.w);
    b1.x = cvtpk(w2.x, w2.y); b1.y = cvtpk(w2.z, w2.w);
    b1.z = cvtpk(w3.x, w3.y); b1.w = cvtpk(w3.z, w3.w);
    char* rb = zbuf + srow * 512;       // key = row&31 = srow for both rows
    *(uint4*)(rb + ((gp ^ srow) * 16))               = a0;
    *(uint4*)(rb + (((gp + 1) ^ srow) * 16))         = a1;
    *(uint4*)(rb + 16384 + ((gp ^ srow) * 16))       = b0;
    *(uint4*)(rb + 16384 + (((gp + 1) ^ srow) * 16)) = b1;
    if ((tid & 15) == 0) {
      ztm[srow]      = ztf * squ + SHIFT;   // SHIFT folded in (free)
      ztm[32 + srow] = ztf * sqw + SHIFT;
    }
  }
  __syncthreads();   // the ONLY barrier

  // ---- K=256 single pass: wave's 32 e-cols = tile (half*8 + wid) ----
  const char* bp = eimg + (size_t)(half * 8 + wid) * 16384 + (size_t)lane * 16;
  short8 Bq[4];   // 4-deep B prefetch queue (static idx after full unroll)
#pragma unroll
  for (int i = 0; i < 4; ++i) Bq[i] = *(const short8*)(bp + i * 1024);

  f32x16 acc0, acc1;
#pragma unroll
  for (int i = 0; i < 16; ++i) { acc0[i] = 0.f; acc1[i] = 0.f; }
  // addr algebra: l31*512 + ((2s+hi)^l31)*16  ==  C0 ^ (s*32)
  const int C0 = l31 * 512 + ((hi * 16) ^ (l31 * 16));
  __builtin_amdgcn_s_setprio(1);
#pragma unroll
  for (int s = 0; s < 16; ++s) {
    short8 Bc = Bq[s & 3];
    if (s + 4 < 16) Bq[s & 3] = *(const short8*)(bp + (s + 4) * 1024);
    const int slot = C0 ^ (s * 32);
    short8 A0 = *(const short8*)(zbuf + slot);            // rows 0..31
    short8 A1 = *(const short8*)(zbuf + slot + 16384);    // rows 32..63
    acc0 = __builtin_amdgcn_mfma_f32_32x32x16_bf16(A0, Bc, acc0, 0, 0, 0);
    acc1 = __builtin_amdgcn_mfma_f32_32x32x16_bf16(A1, Bc, acc1, 0, 0, 0);
  }
  __builtin_amdgcn_s_setprio(0);

  // ---- NO-MAX epilogue: lane = e-col; sum 2^(score+SHIFT) over 64 rows ----
  // C row = rg*32 + (r&3) + 8*(r>>2) + 4*hi -> ztm as float4 at 8j+4hi.
  float s0 = 0.f, s1 = 0.f, s2 = 0.f, s3 = 0.f;
#pragma unroll
  for (int j = 0; j < 4; ++j) {
    float4 z0 = *(const float4*)&ztm[8 * j + 4 * hi];
    float4 z1 = *(const float4*)&ztm[32 + 8 * j + 4 * hi];
    s0 += exp2f(acc0[4 * j]     + z0.x) + exp2f(acc1[4 * j]     + z1.x);
    s1 += exp2f(acc0[4 * j + 1] + z0.y) + exp2f(acc1[4 * j + 1] + z1.y);
    s2 += exp2f(acc0[4 * j + 2] + z0.z) + exp2f(acc1[4 * j + 2] + z1.z);
    s3 += exp2f(acc0[4 * j + 3] + z0.w) + exp2f(acc1[4 * j + 3] + z1.w);
  }
  float sm = (s0 + s1) + (s2 + s3);
  sm += shflx(sm, 32);   // other 32 rows live in partner lane
  if (hi == 0) {   // each col owned by exactly one lane -> direct store
    const int col = half * 256 + wid * 32 + l31;
    wsum[(size_t)rowblk * 512 + col] = sm;   // 2^SHIFT-scaled sum
  }
}

// ---- merge the 8 row-blocks of each 512-row window, add eterm, reduce ----
__global__ void merge_b(const float* __restrict__ wsum,
                        const float* __restrict__ eterm, float* __restrict__ partial) {
  __shared__ float sh[512];
  const int b = blockIdx.x, t = threadIdx.x;
  float s = 0.0f;
#pragma unroll
  for (int i = 0; i < 8; ++i)
    s += wsum[(size_t)(8 * b + i) * 512 + t];
  sh[t] = LN2 * (log2f(s) - SHIFT) + eterm[t];   // back to natural units
  __syncthreads();
  for (int st = 256; st > 0; st >>= 1) {
    if (t < st) sh[t] += sh[t + st];
    __syncthreads();
  }
  if (t == 0) partial[b] = sh[0];
}

__global__ void final_k(const float* __restrict__ partial,
                        const float* __restrict__ lsp, float* __restrict__ out) {
  __shared__ float sh[128];
  const int t = threadIdx.x;
  sh[t] = partial[t];
  __syncthreads();
  for (int st = 64; st > 0; st >>= 1) {
    if (t < st) sh[t] += sh[t + st];
    __syncthreads();
  }
  if (t == 0) {
    float ls = lsp[0];
    out[0] = -sh[0] / 65536.0f + 128.0f * (2.0f * ls - 1.0f) + logf(512.0f);
  }
}

extern "C" void kernel_launch(void* const* d_in, const int* in_sizes, int n_in,
                              void* d_out, int out_size, void* d_ws, size_t ws_size,
                              hipStream_t stream) {
  const float* z   = (const float*)d_in[0];
  const float* e   = (const float*)d_in[1];
  const float* lsp = (const float*)d_in[2];
  float* out = (float*)d_out;
  char* ws = (char*)d_ws;
  char*  eimg    = ws + WS_EIMG;
  float* eterm   = (float*)(ws + WS_ETERM);
  float* wsum    = (float*)(ws + WS_WSUM);
  float* partial = (float*)(ws + WS_PART);

  prep_e<<<dim3(16), dim3(256), 0, stream>>>(e, lsp, eimg, eterm);
  lse_main<<<dim3(2048), dim3(512), 0, stream>>>(z, eimg, lsp, wsum);
  merge_b<<<dim3(128), dim3(512), 0, stream>>>(wsum, eterm, partial);
  final_k<<<dim3(1), dim3(128), 0, stream>>>(partial, lsp, out);
}